// Round 1
// 236.981 us; speedup vs baseline: 1.0370x; 1.0370x over previous
//
#include <hip/hip_runtime.h>

#define NEG (-10000.0f)
#define START_TAG 62
#define STOP_TAG 63
#define SLEN 512
#define BATCH 512
#define NTAG 64

// One wave per batch; lane j = tag j.
// e[i] = exp(trans[i][j]) in VGPRs (amdgpu_waves_per_eu(1,1) -> full VGPR budget).
//
// Round-5 change: the hot loop was latency-bound (VALUBusy 26%, 937 cyc/step
// wall vs ~270 issue), stalled on the depth-2 feats prefetch (~900-1800 cyc
// load latency, 1 wave/SIMD -> nothing hides it). Fix: ring-8 feats prefetch
// (8 outstanding vmcnt loads/wave). The 8x k-chunk code duplication that
// depth-2 was shackled to (mreg[k] compile-time register index) is removed by
// staging the wave-uniform mask column in LDS (uniform ds_read_b32 broadcast,
// in-order lgkmcnt -- NOT the out-of-order SMEM path from the round-4 bug).
// Step s=0 runs as a masked-off dummy (smask[0] forced to 0) so the loop is a
// single flat 64-block x 8-unrolled ring with no peel; steps 1..511 compute
// bit-identical math to the previous kernel.
//
// Scaled linear-space recursion: p_i = exp(alpha_i - C), acc_j = sum_i p_i*E_ij,
// alpha'_j = C + log(acc_j) + f_j. C cancels exactly -> C = readfirstlane(alpha).
__global__ __launch_bounds__(64) __attribute__((amdgpu_waves_per_eu(1, 1)))
void crf_fwd(const float* __restrict__ feats,
             const int* __restrict__ tags,
             const float* __restrict__ mask,
             const float* __restrict__ trans,
             float* __restrict__ diff /* [BATCH] */) {
    const int b = blockIdx.x;
    const int j = threadIdx.x; // tag lane 0..63

    __shared__ float smask[SLEN]; // 2 KB: wave-uniform mask column

    // ---- E column in registers + column sum (for exact analytic step 0) ----
    float e[NTAG];
    float colsum = 0.0f;
#pragma unroll
    for (int i = 0; i < NTAG; ++i) {
        e[i] = __expf(trans[i * NTAG + j]); // exp(NEG) underflows to 0 - desired
        colsum += e[i];
    }
    const float tstop = trans[STOP_TAG * NTAG + j];

    // ---- mask column preload: lane j holds mask[(64k+j)*B + b], k=0..7 ----
    float mreg[8];
#pragma unroll
    for (int k = 0; k < 8; ++k)
        mreg[k] = mask[(64 * k + j) * BATCH + b];

    // stage mask column to LDS for uniform broadcast reads in the hot loop
#pragma unroll
    for (int k = 0; k < 8; ++k)
        smask[64 * k + j] = mreg[k];

    // ---- step 0 (exact analytic; trans[START,:]==NEG) ----
    float f_s0 = feats[(0 * BATCH + b) * NTAG + j];
    float m0 = __uint_as_float(__builtin_amdgcn_readlane(__float_as_uint(mreg[0]), 0));
    float alpha = (m0 > 0.0f) ? (NEG + log1pf(colsum) + f_s0)
                              : ((j == START_TAG) ? 0.0f : NEG);

    // force the s=0 loop iteration to be a no-op (alpha already holds step 0)
    if (j == 0) smask[0] = 0.0f;
    __syncthreads(); // 1 wave: cheap; orders ds_writes before loop ds_reads

    // ---- feats ring prefetch, depth 8 (the ONLY vmcnt loads in the loop) ----
    const float* fp = feats + (size_t)b * NTAG + j;
    float fr[8];
#pragma unroll
    for (int t = 0; t < 8; ++t)
        fr[t] = fp[(size_t)t * BATCH * NTAG];

    for (int blk = 0; blk < 64; ++blk) {
#pragma unroll
        for (int t = 0; t < 8; ++t) {
            const int s = blk * 8 + t;
            const float fc = fr[t];
            int sp = s + 8;
            if (sp > SLEN - 1) sp = SLEN - 1; // tail: clamped garbage, never consumed
            fr[t] = fp[(size_t)sp * BATCH * NTAG];

            // wave-uniform mask broadcast from LDS (in-order lgkmcnt)
            const float mk = smask[s];

            // scaling constant: lane 0's alpha (cancels exactly)
            float C = __uint_as_float(
                __builtin_amdgcn_readfirstlane(__float_as_uint(alpha)));
            float p = __expf(alpha - C);

            // acc_j = sum_i p_i * E[i][j]; readlane broadcast, 4 indep chains
            unsigned pu = __float_as_uint(p);
            float a0 = 0.0f, a1 = 0.0f, a2 = 0.0f, a3 = 0.0f;
#pragma unroll
            for (int i = 0; i < NTAG; i += 4) {
                a0 = fmaf(__uint_as_float(__builtin_amdgcn_readlane(pu, i + 0)), e[i + 0], a0);
                a1 = fmaf(__uint_as_float(__builtin_amdgcn_readlane(pu, i + 1)), e[i + 1], a1);
                a2 = fmaf(__uint_as_float(__builtin_amdgcn_readlane(pu, i + 2)), e[i + 2], a2);
                a3 = fmaf(__uint_as_float(__builtin_amdgcn_readlane(pu, i + 3)), e[i + 3], a3);
            }
            float acc = (a0 + a1) + (a2 + a3);

            float nxt = C + __logf(acc) + fc; // acc==0 (STOP col) -> -inf, benign
            alpha = (mk > 0.0f) ? nxt : alpha;
        }
    }

    // ---- epilogue 1: log_z = logsumexp_j(alpha_j + trans[STOP][j]) ----
    float v = alpha + tstop;
    float m2 = v;
#pragma unroll
    for (int w = 32; w >= 1; w >>= 1)
        m2 = fmaxf(m2, __shfl_xor(m2, w, 64));
    float pe = __expf(v - m2);
#pragma unroll
    for (int w = 32; w >= 1; w >>= 1)
        pe += __shfl_xor(pe, w, 64);
    float logz = m2 + __logf(pe);

    // ---- epilogue 2: true-path score; lanes parallel over time steps ----
    float psc = 0.0f, pms = 0.0f;
#pragma unroll
    for (int k = 0; k < 8; ++k) {
        int s = j + 64 * k;
        int tg = tags[s * BATCH + b];
        float mk = mreg[k]; // this lane's preloaded mask[s]
        int tprev = (s == 0) ? START_TAG : tags[(s - 1) * BATCH + b];
        float em = feats[((size_t)s * BATCH + b) * NTAG + tg];
        psc = fmaf(em + trans[tprev * NTAG + tg], mk, psc);
        pms += mk;
    }
#pragma unroll
    for (int w = 32; w >= 1; w >>= 1) {
        psc += __shfl_xor(psc, w, 64);
        pms += __shfl_xor(pms, w, 64);
    }

    if (j == 0) {
        int last_idx = (int)(pms + 0.5f) - 1;
        int ltag = tags[last_idx * BATCH + b];
        float score = psc + trans[ltag * NTAG + STOP_TAG];
        diff[b] = logz - score;
    }
}

__global__ __launch_bounds__(512) void crf_reduce(const float* __restrict__ diff,
                                                  float* __restrict__ out) {
    __shared__ float sdata[8];
    int t = threadIdx.x;
    float val = diff[t];
#pragma unroll
    for (int w = 32; w >= 1; w >>= 1)
        val += __shfl_xor(val, w, 64);
    if ((t & 63) == 0) sdata[t >> 6] = val;
    __syncthreads();
    if (t == 0) {
        float ssum = 0.0f;
        for (int i = 0; i < 8; ++i) ssum += sdata[i];
        out[0] = ssum * (1.0f / (float)BATCH);
    }
}

extern "C" void kernel_launch(void* const* d_in, const int* in_sizes, int n_in,
                              void* d_out, int out_size, void* d_ws, size_t ws_size,
                              hipStream_t stream) {
    const float* feats = (const float*)d_in[0];
    const int* tags = (const int*)d_in[1];
    const float* mask = (const float*)d_in[2];
    const float* trans = (const float*)d_in[3];
    float* out = (float*)d_out;
    float* diff = (float*)d_ws; // 512 floats

    crf_fwd<<<BATCH, 64, 0, stream>>>(feats, tags, mask, trans, diff);
    crf_reduce<<<1, 512, 0, stream>>>(diff, out);
}